// Round 1
// baseline (1013.515 us; speedup 1.0000x reference)
//
#include <hip/hip_runtime.h>
#include <hip/hip_bf16.h>

// Problem constants
#define BB 2
#define SS 2048
#define DD 1024
#define HH 16
#define KSZ 64

// ---------------------------------------------------------------------------
// Kernel 1: QKV projection.
// C[m, n] = sum_d x[m, d] * W[d, n],  m = b*S+s (4096), n = k*16+h (1024).
// Block computes 64 rows x 256 cols (16 k x all 16 heads). Thread (ty,tx):
// rows ty*4..+3, head h = tx, k = kb*16 + j (j=0..15).
// Output written to qkvT[p][b][h][s][k]  (per-head planes, coalesced 64B rows).
// ---------------------------------------------------------------------------
__global__ __launch_bounds__(256) void proj_kernel(
    const float* __restrict__ x, const float* __restrict__ Wq,
    const float* __restrict__ Wk, const float* __restrict__ Wv,
    float* __restrict__ qkvT) {
  const int kb = blockIdx.x;            // 0..3   -> k0 = kb*16
  const int m0 = blockIdx.y * 64;       // 0..4032
  const int p  = blockIdx.z;            // 0..2
  const float* W = (p == 0) ? Wq : (p == 1) ? Wk : Wv;
  float* outp = qkvT + (size_t)p * (BB * HH * SS * KSZ);

  __shared__ __align__(16) float As[16][68];    // As[kk][mm]  (x tile, transposed)
  __shared__ __align__(16) float Bs[16][260];   // Bs[kk][nn]  nn = (k-k0)*16 + h

  const int tid = threadIdx.x;
  const int tx = tid & 15;              // head
  const int ty = tid >> 4;              // row group
  const int n0 = kb * 256;

  float acc[4][16];
  #pragma unroll
  for (int i = 0; i < 4; ++i)
    #pragma unroll
    for (int j = 0; j < 16; ++j) acc[i][j] = 0.f;

  for (int kt = 0; kt < DD; kt += 16) {
    // stage x tile (64 rows x 16 d), transposed into As
    {
      int mm = tid >> 2;
      int kk4 = (tid & 3) * 4;
      const float4 v = *(const float4*)(x + (size_t)(m0 + mm) * DD + kt + kk4);
      As[kk4 + 0][mm] = v.x; As[kk4 + 1][mm] = v.y;
      As[kk4 + 2][mm] = v.z; As[kk4 + 3][mm] = v.w;
    }
    // stage W tile (16 d x 256 n), natural order
    #pragma unroll
    for (int i = 0; i < 4; ++i) {
      int idx4 = tid + i * 256;               // float4 index, 0..1023
      int kk = idx4 >> 6;
      int nn4 = (idx4 & 63) * 4;
      const float4 v = *(const float4*)(W + (size_t)(kt + kk) * DD + n0 + nn4);
      *(float4*)&Bs[kk][nn4] = v;
    }
    __syncthreads();
    #pragma unroll 4
    for (int kk = 0; kk < 16; ++kk) {
      const float4 a4 = *(const float4*)&As[kk][ty * 4];
      const float a[4] = {a4.x, a4.y, a4.z, a4.w};
      #pragma unroll
      for (int j = 0; j < 16; ++j) {
        const float bv = Bs[kk][j * 16 + tx];
        #pragma unroll
        for (int i = 0; i < 4; ++i) acc[i][j] = fmaf(a[i], bv, acc[i][j]);
      }
    }
    __syncthreads();
  }
  // epilogue: h = tx, k = kb*16 + j  -> 64B contiguous per row
  #pragma unroll
  for (int i = 0; i < 4; ++i) {
    int m = m0 + ty * 4 + i;
    int b = m >> 11, s = m & 2047;
    float* dst = outp + ((size_t)(b * HH + tx) * SS + s) * KSZ + kb * 16;
    #pragma unroll
    for (int j4 = 0; j4 < 4; ++j4) {
      float4 v = make_float4(acc[i][j4 * 4 + 0], acc[i][j4 * 4 + 1],
                             acc[i][j4 * 4 + 2], acc[i][j4 * 4 + 3]);
      *(float4*)(dst + j4 * 4) = v;
    }
  }
}

// ---------------------------------------------------------------------------
// Kernel 2: flash attention per (b, h, 64-query tile), causal.
// Q/K staged transposed in LDS (pad 68 -> aligned b128 reads, 2-way max).
// Online softmax state (m, l, alpha) in LDS; O accumulator in registers.
// Writes heads to headsT[b][h][s][k] (coalesced).
// ---------------------------------------------------------------------------
__global__ __launch_bounds__(256) void attn_kernel(
    const float* __restrict__ qkvT, float* __restrict__ headsT) {
  const int it = blockIdx.x;            // query tile 0..31
  const int h  = blockIdx.y;
  const int b  = blockIdx.z;
  const size_t plane = (size_t)(b * HH + h) * SS * KSZ;
  const size_t PSZ = (size_t)BB * HH * SS * KSZ;
  const float* Qg = qkvT + plane;
  const float* Kg = qkvT + PSZ + plane;
  const float* Vg = qkvT + 2 * PSZ + plane;

  __shared__ __align__(16) float QsT[64][68];
  __shared__ __align__(16) float KsT[64][68];
  __shared__ __align__(16) float Vs [64][68];
  __shared__ __align__(16) float SsT[64][68];
  __shared__ float red[64][17];         // partial max / partial sum
  __shared__ float mrow[64], lrow[64], arow[64];

  const int tid = threadIdx.x;
  const int tx = tid & 15, ty = tid >> 4;
  const int r0 = ty * 4, c0 = tx * 4;

  // load Q tile, transposed
  #pragma unroll
  for (int i = 0; i < 4; ++i) {
    int idx4 = tid + i * 256;
    int r = idx4 >> 4;
    int kk4 = (idx4 & 15) * 4;
    const float4 v = *(const float4*)(Qg + (size_t)(it * 64 + r) * KSZ + kk4);
    QsT[kk4 + 0][r] = v.x; QsT[kk4 + 1][r] = v.y;
    QsT[kk4 + 2][r] = v.z; QsT[kk4 + 3][r] = v.w;
  }
  if (tid < 64) { mrow[tid] = -1e30f; lrow[tid] = 0.f; }

  float o[4][4];
  #pragma unroll
  for (int i = 0; i < 4; ++i)
    #pragma unroll
    for (int j = 0; j < 4; ++j) o[i][j] = 0.f;

  for (int lt = 0; lt <= it; ++lt) {
    __syncthreads();                    // protect KsT/Vs/SsT reuse
    #pragma unroll
    for (int i = 0; i < 4; ++i) {
      int idx4 = tid + i * 256;
      int r = idx4 >> 4;
      int kk4 = (idx4 & 15) * 4;
      const float4 kv = *(const float4*)(Kg + (size_t)(lt * 64 + r) * KSZ + kk4);
      KsT[kk4 + 0][r] = kv.x; KsT[kk4 + 1][r] = kv.y;
      KsT[kk4 + 2][r] = kv.z; KsT[kk4 + 3][r] = kv.w;
      const float4 vv = *(const float4*)(Vg + (size_t)(lt * 64 + r) * KSZ + kk4);
      *(float4*)&Vs[r][kk4] = vv;
    }
    __syncthreads();

    // S = Q @ K^T
    float sacc[4][4];
    #pragma unroll
    for (int i = 0; i < 4; ++i)
      #pragma unroll
      for (int j = 0; j < 4; ++j) sacc[i][j] = 0.f;
    #pragma unroll 4
    for (int kk = 0; kk < 64; ++kk) {
      const float4 a4 = *(const float4*)&QsT[kk][r0];
      const float4 b4 = *(const float4*)&KsT[kk][c0];
      const float a[4] = {a4.x, a4.y, a4.z, a4.w};
      const float bv[4] = {b4.x, b4.y, b4.z, b4.w};
      #pragma unroll
      for (int i = 0; i < 4; ++i)
        #pragma unroll
        for (int j = 0; j < 4; ++j) sacc[i][j] = fmaf(a[i], bv[j], sacc[i][j]);
    }
    // scale + causal mask + per-thread row max
    const bool diag = (lt == it);
    #pragma unroll
    for (int i = 0; i < 4; ++i) {
      float pm = -1e30f;
      #pragma unroll
      for (int j = 0; j < 4; ++j) {
        float sv = sacc[i][j] * 0.125f;
        if (diag && (c0 + j) > (r0 + i)) sv = -1e30f;
        sacc[i][j] = sv;
        pm = fmaxf(pm, sv);
      }
      red[r0 + i][tx] = pm;
    }
    __syncthreads();
    if (tid < 64) {                     // finalize row max, alpha
      float mold = mrow[tid];
      float mx = mold;
      #pragma unroll
      for (int t = 0; t < 16; ++t) mx = fmaxf(mx, red[tid][t]);
      mrow[tid] = mx;
      arow[tid] = __expf(mold - mx);
    }
    __syncthreads();
    // exp + store P^T + partial sums (parallel across all waves)
    #pragma unroll
    for (int i = 0; i < 4; ++i) {
      const float mx = mrow[r0 + i];
      float ps = 0.f;
      #pragma unroll
      for (int j = 0; j < 4; ++j) {
        float pv = __expf(sacc[i][j] - mx);
        SsT[c0 + j][r0 + i] = pv;
        ps += pv;
      }
      red[r0 + i][tx] = ps;
    }
    __syncthreads();
    if (tid < 64) {                     // finalize l
      float ls = 0.f;
      #pragma unroll
      for (int t = 0; t < 16; ++t) ls += red[tid][t];
      lrow[tid] = lrow[tid] * arow[tid] + ls;
    }
    // O = O*alpha + P @ V
    float al[4];
    #pragma unroll
    for (int i = 0; i < 4; ++i) al[i] = arow[r0 + i];
    #pragma unroll
    for (int i = 0; i < 4; ++i)
      #pragma unroll
      for (int j = 0; j < 4; ++j) o[i][j] *= al[i];
    #pragma unroll 4
    for (int kk = 0; kk < 64; ++kk) {
      const float4 a4 = *(const float4*)&SsT[kk][r0];
      const float4 b4 = *(const float4*)&Vs[kk][c0];
      const float a[4] = {a4.x, a4.y, a4.z, a4.w};
      const float bv[4] = {b4.x, b4.y, b4.z, b4.w};
      #pragma unroll
      for (int i = 0; i < 4; ++i)
        #pragma unroll
        for (int j = 0; j < 4; ++j) o[i][j] = fmaf(a[i], bv[j], o[i][j]);
    }
  }
  __syncthreads();
  float inv[4];
  #pragma unroll
  for (int i = 0; i < 4; ++i) inv[i] = 1.0f / lrow[r0 + i];
  #pragma unroll
  for (int i = 0; i < 4; ++i) {
    int srow = it * 64 + r0 + i;
    float* dst = headsT + plane + (size_t)srow * KSZ + c0;
    *(float4*)dst = make_float4(o[i][0] * inv[i], o[i][1] * inv[i],
                                o[i][2] * inv[i], o[i][3] * inv[i]);
  }
}

// ---------------------------------------------------------------------------
// Kernel 3: output projection.
// out[m, n] = sum_{f'=0..1023} A'[m, f'] * Kp[f', n]
//   f' = h*64+k ; A'[m,f'] = headsT[b][h][s][k] ; Kp[f'] = kernel row (k*16+h).
// Block: 32 rows x 64 cols, K-step 16. Grid 128 blocks.
// ---------------------------------------------------------------------------
__global__ __launch_bounds__(256) void out_kernel(
    const float* __restrict__ headsT, const float* __restrict__ kern,
    float* __restrict__ out) {
  const int m0 = blockIdx.x * 32;
  __shared__ __align__(16) float As[16][36];   // As[kk][mm]
  __shared__ __align__(16) float Bs[16][68];
  const int tid = threadIdx.x, tx = tid & 15, ty = tid >> 4;

  float acc[2][4];
  #pragma unroll
  for (int i = 0; i < 2; ++i)
    #pragma unroll
    for (int j = 0; j < 4; ++j) acc[i][j] = 0.f;

  for (int kt = 0; kt < HH * KSZ; kt += 16) {
    {
      int mm = tid >> 3, kk2 = (tid & 7) * 2;
      int m = m0 + mm, b = m >> 11, s = m & 2047;
      int f = kt + kk2, hh = f >> 6, k = f & 63;
      const float2 v = *(const float2*)(headsT +
          ((size_t)(b * HH + hh) * SS + s) * KSZ + k);
      As[kk2 + 0][mm] = v.x; As[kk2 + 1][mm] = v.y;
    }
    {
      int kk = tid >> 4, nn4 = (tid & 15) * 4;
      int f = kt + kk, hh = f >> 6, k = f & 63;
      const float4 v = *(const float4*)(kern + (size_t)(k * HH + hh) * KSZ + nn4);
      *(float4*)&Bs[kk][nn4] = v;
    }
    __syncthreads();
    #pragma unroll 4
    for (int kk = 0; kk < 16; ++kk) {
      const float a0 = As[kk][ty * 2 + 0];
      const float a1 = As[kk][ty * 2 + 1];
      const float4 b4 = *(const float4*)&Bs[kk][tx * 4];
      const float bv[4] = {b4.x, b4.y, b4.z, b4.w};
      #pragma unroll
      for (int j = 0; j < 4; ++j) {
        acc[0][j] = fmaf(a0, bv[j], acc[0][j]);
        acc[1][j] = fmaf(a1, bv[j], acc[1][j]);
      }
    }
    __syncthreads();
  }
  #pragma unroll
  for (int i = 0; i < 2; ++i) {
    int m = m0 + ty * 2 + i;
    *(float4*)(out + (size_t)m * KSZ + tx * 4) =
        make_float4(acc[i][0], acc[i][1], acc[i][2], acc[i][3]);
  }
}

extern "C" void kernel_launch(void* const* d_in, const int* in_sizes, int n_in,
                              void* d_out, int out_size, void* d_ws, size_t ws_size,
                              hipStream_t stream) {
  const float* x    = (const float*)d_in[0];
  const float* Wq   = (const float*)d_in[1];
  const float* Wk   = (const float*)d_in[2];
  const float* Wv   = (const float*)d_in[3];
  const float* kern = (const float*)d_in[4];
  float* out = (float*)d_out;

  float* qkvT   = (float*)d_ws;                                   // 3 * 16 MB
  float* headsT = qkvT + (size_t)3 * BB * HH * SS * KSZ;          // 16 MB

  proj_kernel<<<dim3(4, 64, 3), 256, 0, stream>>>(x, Wq, Wk, Wv, qkvT);
  attn_kernel<<<dim3(32, HH, BB), 256, 0, stream>>>(qkvT, headsT);
  out_kernel<<<dim3(128), 256, 0, stream>>>(headsT, kern, out);
}

// Round 3
// 308.432 us; speedup vs baseline: 3.2860x; 3.2860x over previous
//
#include <hip/hip_runtime.h>
#include <hip/hip_bf16.h>

#define BB 2
#define SS 2048
#define DD 1024
#define HH 16
#define KSZ 64

typedef __attribute__((ext_vector_type(8))) short s16x8;   // MFMA A/B frag (8 bf16)
typedef __attribute__((ext_vector_type(4))) float f32x4;   // MFMA C/D frag
typedef __attribute__((ext_vector_type(8))) unsigned short u16x8;
typedef __attribute__((ext_vector_type(4))) unsigned short u16x4;
typedef unsigned short u16;

__device__ __forceinline__ u16 bf16rne(float f) {
  unsigned int u = __float_as_uint(f);
  unsigned int r = (u + 0x7FFFu + ((u >> 16) & 1u)) >> 16;
  return (u16)r;
}

// ---------------------------------------------------------------------------
// Prep 1: cast x (fp32) -> xb (bf16). 4096*1024 elems, 8/thread.
// ---------------------------------------------------------------------------
__global__ __launch_bounds__(256) void prep_cast(const float* __restrict__ x,
                                                 u16* __restrict__ xb) {
  int idx = (blockIdx.x * 256 + threadIdx.x) * 8;
  float4 a = *(const float4*)(x + idx);
  float4 b = *(const float4*)(x + idx + 4);
  u16x8 v;
  v[0] = bf16rne(a.x); v[1] = bf16rne(a.y); v[2] = bf16rne(a.z); v[3] = bf16rne(a.w);
  v[4] = bf16rne(b.x); v[5] = bf16rne(b.y); v[6] = bf16rne(b.z); v[7] = bf16rne(b.w);
  *(u16x8*)(xb + idx) = v;
}

// ---------------------------------------------------------------------------
// Prep 2: transpose W[d][n] fp32 -> Wt[p][n][d] bf16 (64x64 tiles via LDS).
// ---------------------------------------------------------------------------
__global__ __launch_bounds__(256) void prep_transpose(
    const float* __restrict__ Wq, const float* __restrict__ Wk,
    const float* __restrict__ Wv, u16* __restrict__ Wt) {
  const int p = blockIdx.z;
  const float* W = (p == 0) ? Wq : (p == 1) ? Wk : Wv;
  u16* Wo = Wt + (size_t)p * DD * DD;
  const int d0 = blockIdx.x * 64, n0 = blockIdx.y * 64;
  __shared__ float Ts[64][65];
  const int tid = threadIdx.x;
  #pragma unroll
  for (int i = 0; i < 4; ++i) {
    int f4 = tid + i * 256;
    int r = f4 >> 4, c4 = f4 & 15;
    float4 v = *(const float4*)(W + (size_t)(d0 + r) * DD + n0 + c4 * 4);
    Ts[r][c4 * 4 + 0] = v.x; Ts[r][c4 * 4 + 1] = v.y;
    Ts[r][c4 * 4 + 2] = v.z; Ts[r][c4 * 4 + 3] = v.w;
  }
  __syncthreads();
  #pragma unroll
  for (int i = 0; i < 4; ++i) {
    int ch = tid + i * 256;
    int n = ch >> 4, d4 = ch & 15;
    u16x4 o;
    #pragma unroll
    for (int j = 0; j < 4; ++j) o[j] = bf16rne(Ts[d4 * 4 + j][n]);
    *(u16x4*)(Wo + (size_t)(n0 + n) * DD + d0 + d4 * 4) = o;
  }
}

// ---------------------------------------------------------------------------
// Proj: C = xb(4096x1024) @ W(1024x1024) for p=0..2, bf16 MFMA 16x16x32.
// Block tile 128x128, 4 waves x (4x4 frags), BK=32.
// Epilogue: LDS transpose -> qkvT[p][b][h][s][k] bf16; V (p==2) transposed
// to [b][h][k][s] so attention can stage V^T with coalesced natural loads.
// ---------------------------------------------------------------------------
__global__ __launch_bounds__(256) void proj_kernel(
    const u16* __restrict__ xb, const u16* __restrict__ Wt,
    u16* __restrict__ qkvT) {
  const int n0 = blockIdx.x * 128;
  const int m0 = blockIdx.y * 128;
  const int p  = blockIdx.z;
  const u16* W = Wt + (size_t)p * DD * DD;         // [n][d]
  u16* outp = qkvT + (size_t)p * (BB * HH * SS * KSZ);

  __shared__ __align__(16) unsigned char raw[34816];
  u16* As = (u16*)raw;            // [128][40]  (pitch 40 = 2-way free)
  u16* Bs = As + 128 * 40;        // [128][40]
  u16* Cs = (u16*)raw;            // [128][136] (epilogue reuse)

  const int tid = threadIdx.x;
  const int wave = tid >> 6, lane = tid & 63;
  const int g = lane >> 4, c = lane & 15;
  const int mbase = (wave & 1) * 64, nbase = (wave >> 1) * 64;

  f32x4 acc[4][4];
  #pragma unroll
  for (int i = 0; i < 4; ++i)
    #pragma unroll
    for (int j = 0; j < 4; ++j) acc[i][j] = {0.f, 0.f, 0.f, 0.f};

  for (int kt = 0; kt < DD; kt += 32) {
    __syncthreads();
    #pragma unroll
    for (int i = 0; i < 2; ++i) {
      int chunk = tid + i * 256;          // 512 chunks of 8 bf16
      int r = chunk >> 2, c8 = chunk & 3;
      *(u16x8*)&As[r * 40 + c8 * 8] =
          *(const u16x8*)(xb + (size_t)(m0 + r) * DD + kt + c8 * 8);
      *(u16x8*)&Bs[r * 40 + c8 * 8] =
          *(const u16x8*)(W + (size_t)(n0 + r) * DD + kt + c8 * 8);
    }
    __syncthreads();
    s16x8 af[4], bfr[4];
    #pragma unroll
    for (int mf = 0; mf < 4; ++mf)
      af[mf] = *(const s16x8*)&As[(mbase + mf * 16 + c) * 40 + g * 8];
    #pragma unroll
    for (int nf = 0; nf < 4; ++nf)
      bfr[nf] = *(const s16x8*)&Bs[(nbase + nf * 16 + c) * 40 + g * 8];
    #pragma unroll
    for (int mf = 0; mf < 4; ++mf)
      #pragma unroll
      for (int nf = 0; nf < 4; ++nf)
        acc[mf][nf] = __builtin_amdgcn_mfma_f32_16x16x32_bf16(
            af[mf], bfr[nf], acc[mf][nf], 0, 0, 0);
  }
  __syncthreads();
  // dump C frags (bf16) to Cs[m][n], pitch 136
  #pragma unroll
  for (int mf = 0; mf < 4; ++mf)
    #pragma unroll
    for (int nf = 0; nf < 4; ++nf)
      #pragma unroll
      for (int r = 0; r < 4; ++r)
        Cs[(mbase + mf * 16 + g * 4 + r) * 136 + nbase + nf * 16 + c] =
            bf16rne(acc[mf][nf][r]);
  __syncthreads();
  const int b = m0 >> 11;                  // tile never straddles batch
  if (p < 2) {
    // n = k*16+h: per (h, s) write 8 contiguous k (16B)
    int hh = tid >> 4, si = tid & 15;
    #pragma unroll
    for (int i = 0; i < 8; ++i) {
      int row = i * 16 + si;
      int s = (m0 + row) & 2047;
      u16x8 v;
      #pragma unroll
      for (int kp = 0; kp < 8; ++kp) v[kp] = Cs[row * 136 + kp * 16 + hh];
      *(u16x8*)(outp + ((size_t)(b * HH + hh) * SS + s) * KSZ + (n0 >> 4)) = v;
    }
  } else {
    // V transposed: [b][h][k][s] — per (h,k) write 8 contiguous s (16B)
    const int s0 = m0 & 2047;              // FIX: within-batch row, not global
    #pragma unroll
    for (int i = 0; i < 8; ++i) {
      int chunk = tid + i * 256;           // 2048
      int colid = chunk >> 4;
      int hh = colid >> 3, kp = colid & 7;
      int s8 = chunk & 15;
      u16x8 v;
      #pragma unroll
      for (int j = 0; j < 8; ++j) v[j] = Cs[(s8 * 8 + j) * 136 + kp * 16 + hh];
      *(u16x8*)(outp + ((size_t)(b * HH + hh) * KSZ + (n0 >> 4) + kp) * SS +
                s0 + s8 * 8) = v;
    }
  }
}

// ---------------------------------------------------------------------------
// Attention: flash, bf16 MFMA. Block = (q-tile 64, h, b), 4 waves x 16 q rows.
// Softmax in registers via shfl_xor over lane&15 (C-layout cols).
// P: C-layout -> LDS [q][key] -> A-layout reads (per-wave private region).
// ---------------------------------------------------------------------------
__global__ __launch_bounds__(256) void attn_kernel(
    const u16* __restrict__ qkvT, float* __restrict__ headsT) {
  const int it = blockIdx.x, h = blockIdx.y, b = blockIdx.z;
  const size_t plane = (size_t)(b * HH + h) * SS * KSZ;
  const size_t PSZ = (size_t)BB * HH * SS * KSZ;
  const u16* Qg = qkvT + plane;            // [s][k]
  const u16* Kg = qkvT + PSZ + plane;      // [s][k]
  const u16* Vg = qkvT + 2 * PSZ + plane;  // [k][s]  (transposed by proj)

  __shared__ u16 Qs[64 * 72];   // [q][hd]   pitch 72 (144B, 16B-aligned)
  __shared__ u16 Ks[64 * 72];   // [key][hd]
  __shared__ u16 Vt[64 * 72];   // [hd][key]
  __shared__ u16 Ps[64 * 72];   // [q][key]  (wave w owns rows w*16..+15)

  const int tid = threadIdx.x;
  const int wave = tid >> 6, lane = tid & 63;
  const int g = lane >> 4, c = lane & 15;
  const int wq0 = wave * 16;

  #pragma unroll
  for (int i = 0; i < 2; ++i) {
    int chunk = tid + i * 256;             // 512
    int r = chunk >> 3, c8 = chunk & 7;
    *(u16x8*)&Qs[r * 72 + c8 * 8] =
        *(const u16x8*)(Qg + (size_t)(it * 64 + r) * KSZ + c8 * 8);
  }

  f32x4 o[4];
  #pragma unroll
  for (int nf = 0; nf < 4; ++nf) o[nf] = {0.f, 0.f, 0.f, 0.f};
  float m_i[4], l_i[4];
  #pragma unroll
  for (int r = 0; r < 4; ++r) { m_i[r] = -1e30f; l_i[r] = 0.f; }

  for (int lt = 0; lt <= it; ++lt) {
    __syncthreads();
    #pragma unroll
    for (int i = 0; i < 2; ++i) {
      int chunk = tid + i * 256;
      int r = chunk >> 3, c8 = chunk & 7;
      *(u16x8*)&Ks[r * 72 + c8 * 8] =
          *(const u16x8*)(Kg + (size_t)(lt * 64 + r) * KSZ + c8 * 8);
      *(u16x8*)&Vt[r * 72 + c8 * 8] =
          *(const u16x8*)(Vg + (size_t)r * SS + lt * 64 + c8 * 8);
    }
    __syncthreads();

    // S = Q K^T  (16 q x 64 key per wave)
    f32x4 s[4];
    #pragma unroll
    for (int nf = 0; nf < 4; ++nf) s[nf] = {0.f, 0.f, 0.f, 0.f};
    #pragma unroll
    for (int ks = 0; ks < 2; ++ks) {
      s16x8 aq = *(const s16x8*)&Qs[(wq0 + c) * 72 + ks * 32 + g * 8];
      #pragma unroll
      for (int nf = 0; nf < 4; ++nf) {
        s16x8 bk = *(const s16x8*)&Ks[(nf * 16 + c) * 72 + ks * 32 + g * 8];
        s[nf] = __builtin_amdgcn_mfma_f32_16x16x32_bf16(aq, bk, s[nf], 0, 0, 0);
      }
    }
    // scale + causal mask + online softmax (rows = g*4+r, cols = nf*16+c)
    const bool dg = (lt == it);
    float pmax[4];
    #pragma unroll
    for (int r = 0; r < 4; ++r) {
      int q = g * 4 + r;
      float mx = -1e30f;
      #pragma unroll
      for (int nf = 0; nf < 4; ++nf) {
        float sv = s[nf][r] * 0.125f;
        if (dg && (nf * 16 + c) > (wq0 + q)) sv = -1e30f;
        s[nf][r] = sv;
        mx = fmaxf(mx, sv);
      }
      pmax[r] = mx;
    }
    #pragma unroll
    for (int off = 1; off < 16; off <<= 1)
      #pragma unroll
      for (int r = 0; r < 4; ++r)
        pmax[r] = fmaxf(pmax[r], __shfl_xor(pmax[r], off));
    float alpha[4], psum[4];
    #pragma unroll
    for (int r = 0; r < 4; ++r) {
      float mnew = fmaxf(m_i[r], pmax[r]);
      alpha[r] = __expf(m_i[r] - mnew);
      m_i[r] = mnew;
      float ps = 0.f;
      #pragma unroll
      for (int nf = 0; nf < 4; ++nf) {
        float pv = __expf(s[nf][r] - mnew);
        s[nf][r] = pv;
        ps += pv;
      }
      psum[r] = ps;
    }
    #pragma unroll
    for (int off = 1; off < 16; off <<= 1)
      #pragma unroll
      for (int r = 0; r < 4; ++r) psum[r] += __shfl_xor(psum[r], off);
    #pragma unroll
    for (int r = 0; r < 4; ++r) l_i[r] = l_i[r] * alpha[r] + psum[r];

    // P -> LDS (C layout -> A layout), per-wave private rows
    #pragma unroll
    for (int nf = 0; nf < 4; ++nf)
      #pragma unroll
      for (int r = 0; r < 4; ++r)
        Ps[(wq0 + g * 4 + r) * 72 + nf * 16 + c] = bf16rne(s[nf][r]);
    // rescale O
    #pragma unroll
    for (int nf = 0; nf < 4; ++nf)
      #pragma unroll
      for (int r = 0; r < 4; ++r) o[nf][r] *= alpha[r];
    // O += P V
    #pragma unroll
    for (int ks = 0; ks < 2; ++ks) {
      s16x8 ap = *(const s16x8*)&Ps[(wq0 + c) * 72 + ks * 32 + g * 8];
      #pragma unroll
      for (int nf = 0; nf < 4; ++nf) {
        s16x8 bv = *(const s16x8*)&Vt[(nf * 16 + c) * 72 + ks * 32 + g * 8];
        o[nf] = __builtin_amdgcn_mfma_f32_16x16x32_bf16(ap, bv, o[nf], 0, 0, 0);
      }
    }
  }
  float inv[4];
  #pragma unroll
  for (int r = 0; r < 4; ++r) inv[r] = 1.0f / l_i[r];
  #pragma unroll
  for (int nf = 0; nf < 4; ++nf)
    #pragma unroll
    for (int r = 0; r < 4; ++r) {
      int q = it * 64 + wq0 + g * 4 + r;
      headsT[plane + (size_t)q * KSZ + nf * 16 + c] = o[nf][r] * inv[r];
    }
}

// ---------------------------------------------------------------------------
// Output projection (fp32 VALU).
// ---------------------------------------------------------------------------
__global__ __launch_bounds__(256) void out_kernel(
    const float* __restrict__ headsT, const float* __restrict__ kern,
    float* __restrict__ out) {
  const int m0 = blockIdx.x * 32;
  __shared__ __align__(16) float As[16][36];
  __shared__ __align__(16) float Bs[16][68];
  const int tid = threadIdx.x, tx = tid & 15, ty = tid >> 4;

  float acc[2][4];
  #pragma unroll
  for (int i = 0; i < 2; ++i)
    #pragma unroll
    for (int j = 0; j < 4; ++j) acc[i][j] = 0.f;

  for (int kt = 0; kt < HH * KSZ; kt += 16) {
    {
      int mm = tid >> 3, kk2 = (tid & 7) * 2;
      int m = m0 + mm, b = m >> 11, s = m & 2047;
      int f = kt + kk2, hh = f >> 6, k = f & 63;
      const float2 v = *(const float2*)(headsT +
          ((size_t)(b * HH + hh) * SS + s) * KSZ + k);
      As[kk2 + 0][mm] = v.x; As[kk2 + 1][mm] = v.y;
    }
    {
      int kk = tid >> 4, nn4 = (tid & 15) * 4;
      int f = kt + kk, hh = f >> 6, k = f & 63;
      const float4 v = *(const float4*)(kern + (size_t)(k * HH + hh) * KSZ + nn4);
      *(float4*)&Bs[kk][nn4] = v;
    }
    __syncthreads();
    #pragma unroll 4
    for (int kk = 0; kk < 16; ++kk) {
      const float a0 = As[kk][ty * 2 + 0];
      const float a1 = As[kk][ty * 2 + 1];
      const float4 b4 = *(const float4*)&Bs[kk][tx * 4];
      const float bv[4] = {b4.x, b4.y, b4.z, b4.w};
      #pragma unroll
      for (int j = 0; j < 4; ++j) {
        acc[0][j] = fmaf(a0, bv[j], acc[0][j]);
        acc[1][j] = fmaf(a1, bv[j], acc[1][j]);
      }
    }
    __syncthreads();
  }
  #pragma unroll
  for (int i = 0; i < 2; ++i) {
    int m = m0 + ty * 2 + i;
    *(float4*)(out + (size_t)m * KSZ + tx * 4) =
        make_float4(acc[i][0], acc[i][1], acc[i][2], acc[i][3]);
  }
}

extern "C" void kernel_launch(void* const* d_in, const int* in_sizes, int n_in,
                              void* d_out, int out_size, void* d_ws, size_t ws_size,
                              hipStream_t stream) {
  const float* x    = (const float*)d_in[0];
  const float* Wq   = (const float*)d_in[1];
  const float* Wk   = (const float*)d_in[2];
  const float* Wv   = (const float*)d_in[3];
  const float* kern = (const float*)d_in[4];
  float* out = (float*)d_out;

  u16* xb     = (u16*)d_ws;                         // 4096*1024       = 8.4 MB
  u16* Wt     = xb + (size_t)4096 * 1024;           // 3*1024*1024     = 6.3 MB
  u16* qkvT   = Wt + (size_t)3 * 1024 * 1024;       // 3*2*16*2048*64  = 25.2 MB
  float* headsT = (float*)(qkvT + (size_t)3 * BB * HH * SS * KSZ);  // 16.8 MB

  prep_cast<<<2048, 256, 0, stream>>>(x, xb);
  prep_transpose<<<dim3(16, 16, 3), 256, 0, stream>>>(Wq, Wk, Wv, Wt);
  proj_kernel<<<dim3(8, 32, 3), 256, 0, stream>>>(xb, Wt, qkvT);
  attn_kernel<<<dim3(32, HH, BB), 256, 0, stream>>>(qkvT, headsT);
  out_kernel<<<dim3(128), 256, 0, stream>>>(headsT, kern, out);
}

// Round 4
// 238.681 us; speedup vs baseline: 4.2463x; 1.2922x over previous
//
#include <hip/hip_runtime.h>
#include <hip/hip_bf16.h>

#define BB 2
#define SS 2048
#define DD 1024
#define HH 16
#define KSZ 64

typedef __attribute__((ext_vector_type(8))) short s16x8;   // MFMA A/B frag (8 bf16)
typedef __attribute__((ext_vector_type(4))) float f32x4;   // MFMA C/D frag
typedef __attribute__((ext_vector_type(8))) unsigned short u16x8;
typedef __attribute__((ext_vector_type(4))) unsigned short u16x4;
typedef unsigned short u16;

__device__ __forceinline__ u16 bf16rne(float f) {
  unsigned int u = __float_as_uint(f);
  unsigned int r = (u + 0x7FFFu + ((u >> 16) & 1u)) >> 16;
  return (u16)r;
}

// ---------------------------------------------------------------------------
// Prep 1: cast x (fp32) -> xb (bf16). 4096*1024 elems, 8/thread.
// ---------------------------------------------------------------------------
__global__ __launch_bounds__(256) void prep_cast(const float* __restrict__ x,
                                                 u16* __restrict__ xb) {
  int idx = (blockIdx.x * 256 + threadIdx.x) * 8;
  float4 a = *(const float4*)(x + idx);
  float4 b = *(const float4*)(x + idx + 4);
  u16x8 v;
  v[0] = bf16rne(a.x); v[1] = bf16rne(a.y); v[2] = bf16rne(a.z); v[3] = bf16rne(a.w);
  v[4] = bf16rne(b.x); v[5] = bf16rne(b.y); v[6] = bf16rne(b.z); v[7] = bf16rne(b.w);
  *(u16x8*)(xb + idx) = v;
}

// ---------------------------------------------------------------------------
// Prep 2: transpose W[d][n] fp32 -> Wt[p][n][d] bf16 (64x64 tiles via LDS).
// ---------------------------------------------------------------------------
__global__ __launch_bounds__(256) void prep_transpose(
    const float* __restrict__ Wq, const float* __restrict__ Wk,
    const float* __restrict__ Wv, u16* __restrict__ Wt) {
  const int p = blockIdx.z;
  const float* W = (p == 0) ? Wq : (p == 1) ? Wk : Wv;
  u16* Wo = Wt + (size_t)p * DD * DD;
  const int d0 = blockIdx.x * 64, n0 = blockIdx.y * 64;
  __shared__ float Ts[64][65];
  const int tid = threadIdx.x;
  #pragma unroll
  for (int i = 0; i < 4; ++i) {
    int f4 = tid + i * 256;
    int r = f4 >> 4, c4 = f4 & 15;
    float4 v = *(const float4*)(W + (size_t)(d0 + r) * DD + n0 + c4 * 4);
    Ts[r][c4 * 4 + 0] = v.x; Ts[r][c4 * 4 + 1] = v.y;
    Ts[r][c4 * 4 + 2] = v.z; Ts[r][c4 * 4 + 3] = v.w;
  }
  __syncthreads();
  #pragma unroll
  for (int i = 0; i < 4; ++i) {
    int ch = tid + i * 256;
    int n = ch >> 4, d4 = ch & 15;
    u16x4 o;
    #pragma unroll
    for (int j = 0; j < 4; ++j) o[j] = bf16rne(Ts[d4 * 4 + j][n]);
    *(u16x4*)(Wo + (size_t)(n0 + n) * DD + d0 + d4 * 4) = o;
  }
}

// ---------------------------------------------------------------------------
// Proj: C = xb(4096x1024) @ W(1024x1024) for p=0..2, bf16 MFMA 16x16x32.
// Q plane (p==0) pre-scaled by 0.125 (exact in bf16) so attention skips it.
// V plane (p==2) written transposed [b][h][k][s].
// ---------------------------------------------------------------------------
__global__ __launch_bounds__(256) void proj_kernel(
    const u16* __restrict__ xb, const u16* __restrict__ Wt,
    u16* __restrict__ qkvT) {
  const int n0 = blockIdx.x * 128;
  const int m0 = blockIdx.y * 128;
  const int p  = blockIdx.z;
  const u16* W = Wt + (size_t)p * DD * DD;         // [n][d]
  u16* outp = qkvT + (size_t)p * (BB * HH * SS * KSZ);

  __shared__ __align__(16) unsigned char raw[34816];
  u16* As = (u16*)raw;            // [128][40]
  u16* Bs = As + 128 * 40;        // [128][40]
  u16* Cs = (u16*)raw;            // [128][136] (epilogue reuse)

  const int tid = threadIdx.x;
  const int wave = tid >> 6, lane = tid & 63;
  const int g = lane >> 4, c = lane & 15;
  const int mbase = (wave & 1) * 64, nbase = (wave >> 1) * 64;

  f32x4 acc[4][4];
  #pragma unroll
  for (int i = 0; i < 4; ++i)
    #pragma unroll
    for (int j = 0; j < 4; ++j) acc[i][j] = {0.f, 0.f, 0.f, 0.f};

  for (int kt = 0; kt < DD; kt += 32) {
    __syncthreads();
    #pragma unroll
    for (int i = 0; i < 2; ++i) {
      int chunk = tid + i * 256;
      int r = chunk >> 2, c8 = chunk & 3;
      *(u16x8*)&As[r * 40 + c8 * 8] =
          *(const u16x8*)(xb + (size_t)(m0 + r) * DD + kt + c8 * 8);
      *(u16x8*)&Bs[r * 40 + c8 * 8] =
          *(const u16x8*)(W + (size_t)(n0 + r) * DD + kt + c8 * 8);
    }
    __syncthreads();
    s16x8 af[4], bfr[4];
    #pragma unroll
    for (int mf = 0; mf < 4; ++mf)
      af[mf] = *(const s16x8*)&As[(mbase + mf * 16 + c) * 40 + g * 8];
    #pragma unroll
    for (int nf = 0; nf < 4; ++nf)
      bfr[nf] = *(const s16x8*)&Bs[(nbase + nf * 16 + c) * 40 + g * 8];
    #pragma unroll
    for (int mf = 0; mf < 4; ++mf)
      #pragma unroll
      for (int nf = 0; nf < 4; ++nf)
        acc[mf][nf] = __builtin_amdgcn_mfma_f32_16x16x32_bf16(
            af[mf], bfr[nf], acc[mf][nf], 0, 0, 0);
  }
  __syncthreads();
  const float cscale = (p == 0) ? 0.125f : 1.0f;   // fold 1/sqrt(KS) into Q
  #pragma unroll
  for (int mf = 0; mf < 4; ++mf)
    #pragma unroll
    for (int nf = 0; nf < 4; ++nf)
      #pragma unroll
      for (int r = 0; r < 4; ++r)
        Cs[(mbase + mf * 16 + g * 4 + r) * 136 + nbase + nf * 16 + c] =
            bf16rne(acc[mf][nf][r] * cscale);
  __syncthreads();
  const int b = m0 >> 11;
  if (p < 2) {
    int hh = tid >> 4, si = tid & 15;
    #pragma unroll
    for (int i = 0; i < 8; ++i) {
      int row = i * 16 + si;
      int s = (m0 + row) & 2047;
      u16x8 v;
      #pragma unroll
      for (int kp = 0; kp < 8; ++kp) v[kp] = Cs[row * 136 + kp * 16 + hh];
      *(u16x8*)(outp + ((size_t)(b * HH + hh) * SS + s) * KSZ + (n0 >> 4)) = v;
    }
  } else {
    const int s0 = m0 & 2047;
    #pragma unroll
    for (int i = 0; i < 8; ++i) {
      int chunk = tid + i * 256;
      int colid = chunk >> 4;
      int hh = colid >> 3, kp = colid & 7;
      int s8 = chunk & 15;
      u16x8 v;
      #pragma unroll
      for (int j = 0; j < 8; ++j) v[j] = Cs[(s8 * 8 + j) * 136 + kp * 16 + hh];
      *(u16x8*)(outp + ((size_t)(b * HH + hh) * KSZ + (n0 >> 4) + kp) * SS +
                s0 + s8 * 8) = v;
    }
  }
}

// ---------------------------------------------------------------------------
// Attention v2: transposed-S flash, pair-balanced, register-prefetched.
// Block = (pair pr, h, b); processes q-tiles pr and 31-pr -> uniform 33 iters.
// S^T = K.Q^T  (C col = q = lane&15 -> softmax per-lane, 2 shfl rounds)
// O^T = V^T.P^T (C col = q -> alpha rescale per-lane, no cross-lane fixup)
// ---------------------------------------------------------------------------
__global__ __launch_bounds__(256) void attn_kernel(
    const u16* __restrict__ qkvT, float* __restrict__ headsT) {
  const int pr = blockIdx.x, h = blockIdx.y, b = blockIdx.z;
  const size_t plane = (size_t)(b * HH + h) * SS * KSZ;
  const size_t PSZ = (size_t)BB * HH * SS * KSZ;
  const u16* Qg = qkvT + plane;            // [s][k], pre-scaled by 0.125
  const u16* Kg = qkvT + PSZ + plane;      // [s][k]
  const u16* Vg = qkvT + 2 * PSZ + plane;  // [k][s]

  __shared__ u16 Qs[64 * 72];   // [q][d]
  __shared__ u16 Ks[64 * 72];   // [key][d]
  __shared__ u16 Vt[64 * 72];   // [d][key]
  __shared__ u16 Ps[64 * 72];   // [q][key], wave w owns rows w*16..+15

  const int tid = threadIdx.x;
  const int lane = tid & 63;
  const int g = lane >> 4, c = lane & 15;
  const int wq0 = (tid >> 6) * 16;
  const int sr = tid >> 3, sc = tid & 7;   // staging: rows sr, sr+32; chunk sc

  // prologue: issue loads for half 0 (Q tile pr, KV tile 0)
  u16x8 qr0 = *(const u16x8*)(Qg + (size_t)(pr * 64 + sr) * KSZ + sc * 8);
  u16x8 qr1 = *(const u16x8*)(Qg + (size_t)(pr * 64 + sr + 32) * KSZ + sc * 8);
  u16x8 kr0 = *(const u16x8*)(Kg + (size_t)sr * KSZ + sc * 8);
  u16x8 kr1 = *(const u16x8*)(Kg + (size_t)(sr + 32) * KSZ + sc * 8);
  u16x8 vr0 = *(const u16x8*)(Vg + (size_t)sr * SS + sc * 8);
  u16x8 vr1 = *(const u16x8*)(Vg + (size_t)(sr + 32) * SS + sc * 8);

  #pragma unroll 1
  for (int half = 0; half < 2; ++half) {
    const int it = half ? (31 - pr) : pr;
    const int itn = 31 - pr;               // next half's tile (used when half==0)

    f32x4 o[4];
    #pragma unroll
    for (int mf = 0; mf < 4; ++mf) o[mf] = {0.f, 0.f, 0.f, 0.f};
    float m_i = -1e30f, l_i = 0.f;

    #pragma unroll 1
    for (int lt = 0; lt <= it; ++lt) {
      __syncthreads();                     // LDS consumers done
      if (lt == 0) {
        *(u16x8*)&Qs[sr * 72 + sc * 8] = qr0;
        *(u16x8*)&Qs[(sr + 32) * 72 + sc * 8] = qr1;
      }
      *(u16x8*)&Ks[sr * 72 + sc * 8] = kr0;
      *(u16x8*)&Ks[(sr + 32) * 72 + sc * 8] = kr1;
      *(u16x8*)&Vt[sr * 72 + sc * 8] = vr0;
      *(u16x8*)&Vt[(sr + 32) * 72 + sc * 8] = vr1;
      // prefetch next stage (same half: KV lt+1; half 0 diag: next half's Q+KV0)
      if (lt < it) {
        kr0 = *(const u16x8*)(Kg + (size_t)((lt + 1) * 64 + sr) * KSZ + sc * 8);
        kr1 = *(const u16x8*)(Kg + (size_t)((lt + 1) * 64 + sr + 32) * KSZ + sc * 8);
        vr0 = *(const u16x8*)(Vg + (size_t)sr * SS + (lt + 1) * 64 + sc * 8);
        vr1 = *(const u16x8*)(Vg + (size_t)(sr + 32) * SS + (lt + 1) * 64 + sc * 8);
      } else if (half == 0) {
        qr0 = *(const u16x8*)(Qg + (size_t)(itn * 64 + sr) * KSZ + sc * 8);
        qr1 = *(const u16x8*)(Qg + (size_t)(itn * 64 + sr + 32) * KSZ + sc * 8);
        kr0 = *(const u16x8*)(Kg + (size_t)sr * KSZ + sc * 8);
        kr1 = *(const u16x8*)(Kg + (size_t)(sr + 32) * KSZ + sc * 8);
        vr0 = *(const u16x8*)(Vg + (size_t)sr * SS + sc * 8);
        vr1 = *(const u16x8*)(Vg + (size_t)(sr + 32) * SS + sc * 8);
      }
      __syncthreads();                     // staging visible

      // S^T = K . Q^T : A rows = Ks[key][d], B rows = Qs[q][d]
      f32x4 s[4];
      #pragma unroll
      for (int mf = 0; mf < 4; ++mf) s[mf] = {0.f, 0.f, 0.f, 0.f};
      #pragma unroll
      for (int ks = 0; ks < 2; ++ks) {
        s16x8 bq = *(const s16x8*)&Qs[(wq0 + c) * 72 + ks * 32 + g * 8];
        #pragma unroll
        for (int mf = 0; mf < 4; ++mf) {
          s16x8 ak = *(const s16x8*)&Ks[(mf * 16 + c) * 72 + ks * 32 + g * 8];
          s[mf] = __builtin_amdgcn_mfma_f32_16x16x32_bf16(ak, bq, s[mf], 0, 0, 0);
        }
      }
      // causal mask (diagonal tile only); per-lane softmax over 16 keys
      const int qloc = wq0 + c;            // q within tile; key = mf*16+g*4+r
      if (lt == it) {
        #pragma unroll
        for (int mf = 0; mf < 4; ++mf)
          #pragma unroll
          for (int r = 0; r < 4; ++r)
            if (mf * 16 + g * 4 + r > qloc) s[mf][r] = -1e30f;
      }
      float mx = -1e30f;
      #pragma unroll
      for (int mf = 0; mf < 4; ++mf)
        #pragma unroll
        for (int r = 0; r < 4; ++r) mx = fmaxf(mx, s[mf][r]);
      mx = fmaxf(mx, __shfl_xor(mx, 16));
      mx = fmaxf(mx, __shfl_xor(mx, 32));
      const float mnew = fmaxf(m_i, mx);
      const float alpha = __expf(m_i - mnew);
      m_i = mnew;
      float ps = 0.f;
      #pragma unroll
      for (int mf = 0; mf < 4; ++mf) {
        u16x4 pk;
        #pragma unroll
        for (int r = 0; r < 4; ++r) {
          float pv = __expf(s[mf][r] - mnew);
          ps += pv;
          pk[r] = bf16rne(pv);
        }
        *(u16x4*)&Ps[(wq0 + c) * 72 + mf * 16 + g * 4] = pk;  // P^T b64 store
      }
      ps += __shfl_xor(ps, 16);
      ps += __shfl_xor(ps, 32);
      l_i = l_i * alpha + ps;
      // O^T rescale + accumulate: A rows = Vt[d][key], B rows = Ps[q][key]
      #pragma unroll
      for (int mf = 0; mf < 4; ++mf)
        #pragma unroll
        for (int r = 0; r < 4; ++r) o[mf][r] *= alpha;
      #pragma unroll
      for (int ks = 0; ks < 2; ++ks) {
        s16x8 bp = *(const s16x8*)&Ps[(wq0 + c) * 72 + ks * 32 + g * 8];
        #pragma unroll
        for (int mf = 0; mf < 4; ++mf) {
          s16x8 av = *(const s16x8*)&Vt[(mf * 16 + c) * 72 + ks * 32 + g * 8];
          o[mf] = __builtin_amdgcn_mfma_f32_16x16x32_bf16(av, bp, o[mf], 0, 0, 0);
        }
      }
    }
    // epilogue: O^T col q = c, row d = mf*16+g*4+r
    const float inv = 1.0f / l_i;
    const int q = it * 64 + wq0 + c;
    #pragma unroll
    for (int mf = 0; mf < 4; ++mf) {
      float4 v = make_float4(o[mf][0] * inv, o[mf][1] * inv,
                             o[mf][2] * inv, o[mf][3] * inv);
      *(float4*)(headsT + plane + (size_t)q * KSZ + mf * 16 + g * 4) = v;
    }
  }
}

// ---------------------------------------------------------------------------
// Output projection (fp32 VALU).
// ---------------------------------------------------------------------------
__global__ __launch_bounds__(256) void out_kernel(
    const float* __restrict__ headsT, const float* __restrict__ kern,
    float* __restrict__ out) {
  const int m0 = blockIdx.x * 32;
  __shared__ __align__(16) float As[16][36];
  __shared__ __align__(16) float Bs[16][68];
  const int tid = threadIdx.x, tx = tid & 15, ty = tid >> 4;

  float acc[2][4];
  #pragma unroll
  for (int i = 0; i < 2; ++i)
    #pragma unroll
    for (int j = 0; j < 4; ++j) acc[i][j] = 0.f;

  for (int kt = 0; kt < HH * KSZ; kt += 16) {
    {
      int mm = tid >> 3, kk2 = (tid & 7) * 2;
      int m = m0 + mm, b = m >> 11, s = m & 2047;
      int f = kt + kk2, hh = f >> 6, k = f & 63;
      const float2 v = *(const float2*)(headsT +
          ((size_t)(b * HH + hh) * SS + s) * KSZ + k);
      As[kk2 + 0][mm] = v.x; As[kk2 + 1][mm] = v.y;
    }
    {
      int kk = tid >> 4, nn4 = (tid & 15) * 4;
      int f = kt + kk, hh = f >> 6, k = f & 63;
      const float4 v = *(const float4*)(kern + (size_t)(k * HH + hh) * KSZ + nn4);
      *(float4*)&Bs[kk][nn4] = v;
    }
    __syncthreads();
    #pragma unroll 4
    for (int kk = 0; kk < 16; ++kk) {
      const float a0 = As[kk][ty * 2 + 0];
      const float a1 = As[kk][ty * 2 + 1];
      const float4 b4 = *(const float4*)&Bs[kk][tx * 4];
      const float bv[4] = {b4.x, b4.y, b4.z, b4.w};
      #pragma unroll
      for (int j = 0; j < 4; ++j) {
        acc[0][j] = fmaf(a0, bv[j], acc[0][j]);
        acc[1][j] = fmaf(a1, bv[j], acc[1][j]);
      }
    }
    __syncthreads();
  }
  #pragma unroll
  for (int i = 0; i < 2; ++i) {
    int m = m0 + ty * 2 + i;
    *(float4*)(out + (size_t)m * KSZ + tx * 4) =
        make_float4(acc[i][0], acc[i][1], acc[i][2], acc[i][3]);
  }
}

extern "C" void kernel_launch(void* const* d_in, const int* in_sizes, int n_in,
                              void* d_out, int out_size, void* d_ws, size_t ws_size,
                              hipStream_t stream) {
  const float* x    = (const float*)d_in[0];
  const float* Wq   = (const float*)d_in[1];
  const float* Wk   = (const float*)d_in[2];
  const float* Wv   = (const float*)d_in[3];
  const float* kern = (const float*)d_in[4];
  float* out = (float*)d_out;

  u16* xb     = (u16*)d_ws;
  u16* Wt     = xb + (size_t)4096 * 1024;
  u16* qkvT   = Wt + (size_t)3 * 1024 * 1024;
  float* headsT = (float*)(qkvT + (size_t)3 * BB * HH * SS * KSZ);

  prep_cast<<<2048, 256, 0, stream>>>(x, xb);
  prep_transpose<<<dim3(16, 16, 3), 256, 0, stream>>>(Wq, Wk, Wv, Wt);
  proj_kernel<<<dim3(8, 32, 3), 256, 0, stream>>>(xb, Wt, qkvT);
  attn_kernel<<<dim3(16, HH, BB), 256, 0, stream>>>(qkvT, headsT);
  out_kernel<<<dim3(128), 256, 0, stream>>>(headsT, kern, out);
}

// Round 5
// 193.513 us; speedup vs baseline: 5.2375x; 1.2334x over previous
//
#include <hip/hip_runtime.h>
#include <hip/hip_bf16.h>

#define BB 2
#define SS 2048
#define DD 1024
#define HH 16
#define KSZ 64

typedef __attribute__((ext_vector_type(8))) short s16x8;   // MFMA A/B frag (8 bf16)
typedef __attribute__((ext_vector_type(4))) float f32x4;   // MFMA C/D frag
typedef __attribute__((ext_vector_type(8))) unsigned short u16x8;
typedef __attribute__((ext_vector_type(4))) unsigned short u16x4;
typedef unsigned short u16;

__device__ __forceinline__ u16 bf16rne(float f) {
  unsigned int u = __float_as_uint(f);
  unsigned int r = (u + 0x7FFFu + ((u >> 16) & 1u)) >> 16;
  return (u16)r;
}

// ---------------------------------------------------------------------------
// Prep 1: cast x (fp32) -> xb (bf16). 4096*1024 elems, 8/thread.
// ---------------------------------------------------------------------------
__global__ __launch_bounds__(256) void prep_cast(const float* __restrict__ x,
                                                 u16* __restrict__ xb) {
  int idx = (blockIdx.x * 256 + threadIdx.x) * 8;
  float4 a = *(const float4*)(x + idx);
  float4 b = *(const float4*)(x + idx + 4);
  u16x8 v;
  v[0] = bf16rne(a.x); v[1] = bf16rne(a.y); v[2] = bf16rne(a.z); v[3] = bf16rne(a.w);
  v[4] = bf16rne(b.x); v[5] = bf16rne(b.y); v[6] = bf16rne(b.z); v[7] = bf16rne(b.w);
  *(u16x8*)(xb + idx) = v;
}

// ---------------------------------------------------------------------------
// Prep 2: transpose W[d][n] fp32 -> Wt[p][n][d] bf16 (64x64 tiles via LDS).
// ---------------------------------------------------------------------------
__global__ __launch_bounds__(256) void prep_transpose(
    const float* __restrict__ Wq, const float* __restrict__ Wk,
    const float* __restrict__ Wv, u16* __restrict__ Wt) {
  const int p = blockIdx.z;
  const float* W = (p == 0) ? Wq : (p == 1) ? Wk : Wv;
  u16* Wo = Wt + (size_t)p * DD * DD;
  const int d0 = blockIdx.x * 64, n0 = blockIdx.y * 64;
  __shared__ float Ts[64][65];
  const int tid = threadIdx.x;
  #pragma unroll
  for (int i = 0; i < 4; ++i) {
    int f4 = tid + i * 256;
    int r = f4 >> 4, c4 = f4 & 15;
    float4 v = *(const float4*)(W + (size_t)(d0 + r) * DD + n0 + c4 * 4);
    Ts[r][c4 * 4 + 0] = v.x; Ts[r][c4 * 4 + 1] = v.y;
    Ts[r][c4 * 4 + 2] = v.z; Ts[r][c4 * 4 + 3] = v.w;
  }
  __syncthreads();
  #pragma unroll
  for (int i = 0; i < 4; ++i) {
    int ch = tid + i * 256;
    int n = ch >> 4, d4 = ch & 15;
    u16x4 o;
    #pragma unroll
    for (int j = 0; j < 4; ++j) o[j] = bf16rne(Ts[d4 * 4 + j][n]);
    *(u16x4*)(Wo + (size_t)(n0 + n) * DD + d0 + d4 * 4) = o;
  }
}

// ---------------------------------------------------------------------------
// Prep 3: out-weight permute+cast: BpT[n][k'] = kernel[(k*16+h)][n], k'=h*64+k.
// 64 rows x 1024 cols bf16 (128 KB). Grid 64 x 256 threads, 4 elems/thread.
// ---------------------------------------------------------------------------
__global__ __launch_bounds__(256) void prep_wout(const float* __restrict__ kern,
                                                 u16* __restrict__ BpT) {
  const int n = blockIdx.x;
  const int k4 = threadIdx.x * 4;
  u16x4 o;
  #pragma unroll
  for (int j = 0; j < 4; ++j) {
    int kp = k4 + j;
    int h = kp >> 6, k = kp & 63;
    o[j] = bf16rne(kern[(size_t)(k * HH + h) * KSZ + n]);
  }
  *(u16x4*)(BpT + (size_t)n * (HH * KSZ) + k4) = o;
}

// ---------------------------------------------------------------------------
// Proj: C = xb(4096x1024) @ W(1024x1024) for p=0..2, bf16 MFMA 16x16x32.
// Q plane (p==0) pre-scaled by 0.125. V plane (p==2) transposed [b][h][k][s].
// ---------------------------------------------------------------------------
__global__ __launch_bounds__(256) void proj_kernel(
    const u16* __restrict__ xb, const u16* __restrict__ Wt,
    u16* __restrict__ qkvT) {
  const int n0 = blockIdx.x * 128;
  const int m0 = blockIdx.y * 128;
  const int p  = blockIdx.z;
  const u16* W = Wt + (size_t)p * DD * DD;         // [n][d]
  u16* outp = qkvT + (size_t)p * (BB * HH * SS * KSZ);

  __shared__ __align__(16) unsigned char raw[34816];
  u16* As = (u16*)raw;            // [128][40]
  u16* Bs = As + 128 * 40;        // [128][40]
  u16* Cs = (u16*)raw;            // [128][136] (epilogue reuse)

  const int tid = threadIdx.x;
  const int wave = tid >> 6, lane = tid & 63;
  const int g = lane >> 4, c = lane & 15;
  const int mbase = (wave & 1) * 64, nbase = (wave >> 1) * 64;

  f32x4 acc[4][4];
  #pragma unroll
  for (int i = 0; i < 4; ++i)
    #pragma unroll
    for (int j = 0; j < 4; ++j) acc[i][j] = {0.f, 0.f, 0.f, 0.f};

  for (int kt = 0; kt < DD; kt += 32) {
    __syncthreads();
    #pragma unroll
    for (int i = 0; i < 2; ++i) {
      int chunk = tid + i * 256;
      int r = chunk >> 2, c8 = chunk & 3;
      *(u16x8*)&As[r * 40 + c8 * 8] =
          *(const u16x8*)(xb + (size_t)(m0 + r) * DD + kt + c8 * 8);
      *(u16x8*)&Bs[r * 40 + c8 * 8] =
          *(const u16x8*)(W + (size_t)(n0 + r) * DD + kt + c8 * 8);
    }
    __syncthreads();
    s16x8 af[4], bfr[4];
    #pragma unroll
    for (int mf = 0; mf < 4; ++mf)
      af[mf] = *(const s16x8*)&As[(mbase + mf * 16 + c) * 40 + g * 8];
    #pragma unroll
    for (int nf = 0; nf < 4; ++nf)
      bfr[nf] = *(const s16x8*)&Bs[(nbase + nf * 16 + c) * 40 + g * 8];
    #pragma unroll
    for (int mf = 0; mf < 4; ++mf)
      #pragma unroll
      for (int nf = 0; nf < 4; ++nf)
        acc[mf][nf] = __builtin_amdgcn_mfma_f32_16x16x32_bf16(
            af[mf], bfr[nf], acc[mf][nf], 0, 0, 0);
  }
  __syncthreads();
  const float cscale = (p == 0) ? 0.125f : 1.0f;   // fold 1/sqrt(KS) into Q
  #pragma unroll
  for (int mf = 0; mf < 4; ++mf)
    #pragma unroll
    for (int nf = 0; nf < 4; ++nf)
      #pragma unroll
      for (int r = 0; r < 4; ++r)
        Cs[(mbase + mf * 16 + g * 4 + r) * 136 + nbase + nf * 16 + c] =
            bf16rne(acc[mf][nf][r] * cscale);
  __syncthreads();
  const int b = m0 >> 11;
  if (p < 2) {
    int hh = tid >> 4, si = tid & 15;
    #pragma unroll
    for (int i = 0; i < 8; ++i) {
      int row = i * 16 + si;
      int s = (m0 + row) & 2047;
      u16x8 v;
      #pragma unroll
      for (int kp = 0; kp < 8; ++kp) v[kp] = Cs[row * 136 + kp * 16 + hh];
      *(u16x8*)(outp + ((size_t)(b * HH + hh) * SS + s) * KSZ + (n0 >> 4)) = v;
    }
  } else {
    const int s0 = m0 & 2047;
    #pragma unroll
    for (int i = 0; i < 8; ++i) {
      int chunk = tid + i * 256;
      int colid = chunk >> 4;
      int hh = colid >> 3, kp = colid & 7;
      int s8 = chunk & 15;
      u16x8 v;
      #pragma unroll
      for (int j = 0; j < 8; ++j) v[j] = Cs[(s8 * 8 + j) * 136 + kp * 16 + hh];
      *(u16x8*)(outp + ((size_t)(b * HH + hh) * KSZ + (n0 >> 4) + kp) * SS +
                s0 + s8 * 8) = v;
    }
  }
}

// ---------------------------------------------------------------------------
// Attention v2: transposed-S flash, pair-balanced, register-prefetched.
// Epilogue now writes heads in bf16 to headsB[b][h][s][k].
// ---------------------------------------------------------------------------
__global__ __launch_bounds__(256) void attn_kernel(
    const u16* __restrict__ qkvT, u16* __restrict__ headsB) {
  const int pr = blockIdx.x, h = blockIdx.y, b = blockIdx.z;
  const size_t plane = (size_t)(b * HH + h) * SS * KSZ;
  const size_t PSZ = (size_t)BB * HH * SS * KSZ;
  const u16* Qg = qkvT + plane;            // [s][k], pre-scaled by 0.125
  const u16* Kg = qkvT + PSZ + plane;      // [s][k]
  const u16* Vg = qkvT + 2 * PSZ + plane;  // [k][s]

  __shared__ u16 Qs[64 * 72];   // [q][d]
  __shared__ u16 Ks[64 * 72];   // [key][d]
  __shared__ u16 Vt[64 * 72];   // [d][key]
  __shared__ u16 Ps[64 * 72];   // [q][key], wave w owns rows w*16..+15

  const int tid = threadIdx.x;
  const int lane = tid & 63;
  const int g = lane >> 4, c = lane & 15;
  const int wq0 = (tid >> 6) * 16;
  const int sr = tid >> 3, sc = tid & 7;

  u16x8 qr0 = *(const u16x8*)(Qg + (size_t)(pr * 64 + sr) * KSZ + sc * 8);
  u16x8 qr1 = *(const u16x8*)(Qg + (size_t)(pr * 64 + sr + 32) * KSZ + sc * 8);
  u16x8 kr0 = *(const u16x8*)(Kg + (size_t)sr * KSZ + sc * 8);
  u16x8 kr1 = *(const u16x8*)(Kg + (size_t)(sr + 32) * KSZ + sc * 8);
  u16x8 vr0 = *(const u16x8*)(Vg + (size_t)sr * SS + sc * 8);
  u16x8 vr1 = *(const u16x8*)(Vg + (size_t)(sr + 32) * SS + sc * 8);

  #pragma unroll 1
  for (int half = 0; half < 2; ++half) {
    const int it = half ? (31 - pr) : pr;
    const int itn = 31 - pr;

    f32x4 o[4];
    #pragma unroll
    for (int mf = 0; mf < 4; ++mf) o[mf] = {0.f, 0.f, 0.f, 0.f};
    float m_i = -1e30f, l_i = 0.f;

    #pragma unroll 1
    for (int lt = 0; lt <= it; ++lt) {
      __syncthreads();
      if (lt == 0) {
        *(u16x8*)&Qs[sr * 72 + sc * 8] = qr0;
        *(u16x8*)&Qs[(sr + 32) * 72 + sc * 8] = qr1;
      }
      *(u16x8*)&Ks[sr * 72 + sc * 8] = kr0;
      *(u16x8*)&Ks[(sr + 32) * 72 + sc * 8] = kr1;
      *(u16x8*)&Vt[sr * 72 + sc * 8] = vr0;
      *(u16x8*)&Vt[(sr + 32) * 72 + sc * 8] = vr1;
      if (lt < it) {
        kr0 = *(const u16x8*)(Kg + (size_t)((lt + 1) * 64 + sr) * KSZ + sc * 8);
        kr1 = *(const u16x8*)(Kg + (size_t)((lt + 1) * 64 + sr + 32) * KSZ + sc * 8);
        vr0 = *(const u16x8*)(Vg + (size_t)sr * SS + (lt + 1) * 64 + sc * 8);
        vr1 = *(const u16x8*)(Vg + (size_t)(sr + 32) * SS + (lt + 1) * 64 + sc * 8);
      } else if (half == 0) {
        qr0 = *(const u16x8*)(Qg + (size_t)(itn * 64 + sr) * KSZ + sc * 8);
        qr1 = *(const u16x8*)(Qg + (size_t)(itn * 64 + sr + 32) * KSZ + sc * 8);
        kr0 = *(const u16x8*)(Kg + (size_t)sr * KSZ + sc * 8);
        kr1 = *(const u16x8*)(Kg + (size_t)(sr + 32) * KSZ + sc * 8);
        vr0 = *(const u16x8*)(Vg + (size_t)sr * SS + sc * 8);
        vr1 = *(const u16x8*)(Vg + (size_t)(sr + 32) * SS + sc * 8);
      }
      __syncthreads();

      f32x4 s[4];
      #pragma unroll
      for (int mf = 0; mf < 4; ++mf) s[mf] = {0.f, 0.f, 0.f, 0.f};
      #pragma unroll
      for (int ks = 0; ks < 2; ++ks) {
        s16x8 bq = *(const s16x8*)&Qs[(wq0 + c) * 72 + ks * 32 + g * 8];
        #pragma unroll
        for (int mf = 0; mf < 4; ++mf) {
          s16x8 ak = *(const s16x8*)&Ks[(mf * 16 + c) * 72 + ks * 32 + g * 8];
          s[mf] = __builtin_amdgcn_mfma_f32_16x16x32_bf16(ak, bq, s[mf], 0, 0, 0);
        }
      }
      const int qloc = wq0 + c;
      if (lt == it) {
        #pragma unroll
        for (int mf = 0; mf < 4; ++mf)
          #pragma unroll
          for (int r = 0; r < 4; ++r)
            if (mf * 16 + g * 4 + r > qloc) s[mf][r] = -1e30f;
      }
      float mx = -1e30f;
      #pragma unroll
      for (int mf = 0; mf < 4; ++mf)
        #pragma unroll
        for (int r = 0; r < 4; ++r) mx = fmaxf(mx, s[mf][r]);
      mx = fmaxf(mx, __shfl_xor(mx, 16));
      mx = fmaxf(mx, __shfl_xor(mx, 32));
      const float mnew = fmaxf(m_i, mx);
      const float alpha = __expf(m_i - mnew);
      m_i = mnew;
      float ps = 0.f;
      #pragma unroll
      for (int mf = 0; mf < 4; ++mf) {
        u16x4 pk;
        #pragma unroll
        for (int r = 0; r < 4; ++r) {
          float pv = __expf(s[mf][r] - mnew);
          ps += pv;
          pk[r] = bf16rne(pv);
        }
        *(u16x4*)&Ps[(wq0 + c) * 72 + mf * 16 + g * 4] = pk;
      }
      ps += __shfl_xor(ps, 16);
      ps += __shfl_xor(ps, 32);
      l_i = l_i * alpha + ps;
      #pragma unroll
      for (int mf = 0; mf < 4; ++mf)
        #pragma unroll
        for (int r = 0; r < 4; ++r) o[mf][r] *= alpha;
      #pragma unroll
      for (int ks = 0; ks < 2; ++ks) {
        s16x8 bp = *(const s16x8*)&Ps[(wq0 + c) * 72 + ks * 32 + g * 8];
        #pragma unroll
        for (int mf = 0; mf < 4; ++mf) {
          s16x8 av = *(const s16x8*)&Vt[(mf * 16 + c) * 72 + ks * 32 + g * 8];
          o[mf] = __builtin_amdgcn_mfma_f32_16x16x32_bf16(av, bp, o[mf], 0, 0, 0);
        }
      }
    }
    const float inv = 1.0f / l_i;
    const int q = it * 64 + wq0 + c;
    #pragma unroll
    for (int mf = 0; mf < 4; ++mf) {
      u16x4 hv;
      #pragma unroll
      for (int r = 0; r < 4; ++r) hv[r] = bf16rne(o[mf][r] * inv);
      *(u16x4*)(headsB + plane + (size_t)q * KSZ + mf * 16 + g * 4) = hv;
    }
  }
}

// ---------------------------------------------------------------------------
// Out v2: out[m][n] = sum_k' heads'[m][k'] * BpT[n][k'],  M=4096 N=64 K=1024.
// 256 blocks x 16 rows; 4 waves split K (256 each); frags loaded straight
// from global (16B/lane); LDS cross-wave reduce; coalesced float4 stores.
// ---------------------------------------------------------------------------
__global__ __launch_bounds__(256) void out_kernel(
    const u16* __restrict__ headsB, const u16* __restrict__ BpT,
    float* __restrict__ out) {
  const int m0 = blockIdx.x * 16;
  const int tid = threadIdx.x;
  const int wave = tid >> 6, lane = tid & 63;
  const int g = lane >> 4, c = lane & 15;

  const int m = m0 + c;
  const int b = m >> 11, s = m & 2047;

  f32x4 acc[4];
  #pragma unroll
  for (int nf = 0; nf < 4; ++nf) acc[nf] = {0.f, 0.f, 0.f, 0.f};

  #pragma unroll
  for (int it = 0; it < 8; ++it) {
    const int kb = wave * 256 + it * 32;            // K-chunk base
    const int hh = kb >> 6, kk = (kb & 63) + g * 8; // within-head offset
    s16x8 a = *(const s16x8*)(headsB +
        ((size_t)(b * HH + hh) * SS + s) * KSZ + kk);
    #pragma unroll
    for (int nf = 0; nf < 4; ++nf) {
      s16x8 bf = *(const s16x8*)(BpT +
          (size_t)(nf * 16 + c) * (HH * KSZ) + kb + g * 8);
      acc[nf] = __builtin_amdgcn_mfma_f32_16x16x32_bf16(a, bf, acc[nf], 0, 0, 0);
    }
  }

  __shared__ __align__(16) float red[4][64][16];
  #pragma unroll
  for (int nf = 0; nf < 4; ++nf)
    *(f32x4*)&red[wave][lane][nf * 4] = acc[nf];
  __syncthreads();

  // thread t -> output (mi = t>>4, cols (t&15)*4 .. +3)
  const int mi = tid >> 4, n4 = (tid & 15) * 4;
  const int gg = mi >> 2, rr = mi & 3;
  float4 res;
  float* rp = &res.x;
  #pragma unroll
  for (int j = 0; j < 4; ++j) {
    int n = n4 + j;
    int cc = n & 15, nf = n >> 4;
    rp[j] = red[0][gg * 16 + cc][nf * 4 + rr] + red[1][gg * 16 + cc][nf * 4 + rr] +
            red[2][gg * 16 + cc][nf * 4 + rr] + red[3][gg * 16 + cc][nf * 4 + rr];
  }
  *(float4*)(out + (size_t)(m0 + mi) * KSZ + n4) = res;
}

extern "C" void kernel_launch(void* const* d_in, const int* in_sizes, int n_in,
                              void* d_out, int out_size, void* d_ws, size_t ws_size,
                              hipStream_t stream) {
  const float* x    = (const float*)d_in[0];
  const float* Wq   = (const float*)d_in[1];
  const float* Wk   = (const float*)d_in[2];
  const float* Wv   = (const float*)d_in[3];
  const float* kern = (const float*)d_in[4];
  float* out = (float*)d_out;

  u16* xb     = (u16*)d_ws;                          // 8.4 MB
  u16* Wt     = xb + (size_t)4096 * 1024;            // 6.3 MB
  u16* qkvT   = Wt + (size_t)3 * 1024 * 1024;        // 25.2 MB
  u16* headsB = qkvT + (size_t)3 * BB * HH * SS * KSZ;  // 8.4 MB
  u16* BpT    = headsB + (size_t)BB * HH * SS * KSZ;    // 0.13 MB

  prep_cast<<<2048, 256, 0, stream>>>(x, xb);
  prep_transpose<<<dim3(16, 16, 3), 256, 0, stream>>>(Wq, Wk, Wv, Wt);
  prep_wout<<<64, 256, 0, stream>>>(kern, BpT);
  proj_kernel<<<dim3(8, 32, 3), 256, 0, stream>>>(xb, Wt, qkvT);
  attn_kernel<<<dim3(16, HH, BB), 256, 0, stream>>>(qkvT, headsB);
  out_kernel<<<dim3(256), 256, 0, stream>>>(headsB, BpT, out);
}